// Round 8
// baseline (91.237 us; speedup 1.0000x reference)
//
#include <hip/hip_runtime.h>
#include <stdint.h>

#define NPRED   16384
#define NGT     128
#define KSEL    64
#define CAP     512
#define G       4          // gts per block (register-shared scan)
#define THREADS 1024       // 16 waves: full CU occupancy at 2 blocks/CU
#define T0SQ    (0.055f * 0.055f)   // initial squared radius (E[C] ~ 155)

typedef unsigned long long u64;

// Outputs (float32, concatenated): ious[16*128*64], mask[...], k_idx[...]
#define OUT_IOUS 0
#define OUT_MASK (16 * NGT * KSEL)
#define OUT_KIDX (2 * 16 * NGT * KSEL)

// numpy-exact pairwise sum of 64 per-lane values (n=64: 8 strided partials,
// then ((r0+r1)+(r2+r3)) + ((r4+r5)+(r6+r7))). All lanes return the sum.
// Validated bit-exact (absmax=0) in R2-R7.
__device__ __forceinline__ float npsum64(float v, int lane) {
    const int j = lane & 7;
    float r = __shfl(v, j, 64);                       // a[j]
    #pragma unroll
    for (int k = 1; k < 8; ++k)
        r = __fadd_rn(r, __shfl(v, j + 8 * k, 64));   // += a[j+8k], in order
    const float r0 = __shfl(r, 0, 64), r1 = __shfl(r, 1, 64),
                r2 = __shfl(r, 2, 64), r3 = __shfl(r, 3, 64),
                r4 = __shfl(r, 4, 64), r5 = __shfl(r, 5, 64),
                r6 = __shfl(r, 6, 64), r7 = __shfl(r, 7, 64);
    return __fadd_rn(__fadd_rn(__fadd_rn(r0, r1), __fadd_rn(r2, r3)),
                     __fadd_rn(__fadd_rn(r4, r5), __fadd_rn(r6, r7)));
}

__global__ __launch_bounds__(THREADS) void atss_fused(
    const float* __restrict__ pred,  // [16][16384][4] cxcywh
    const float* __restrict__ gt,    // [16][128][4]  cxcywh
    float* __restrict__ out)
{
    __shared__ u64 cand[G][CAP];
    __shared__ u64 topk[G][KSEL];
    __shared__ int s_cnt[G];

    const int tid  = threadIdx.x;
    const int bid  = blockIdx.x;
    const int base_task = bid * G;          // 4 consecutive gts, same batch
    const int b    = base_task >> 7;

    // gt centers for the 4 gts (block-uniform scalar loads)
    float gx[G], gy[G];
    #pragma unroll
    for (int g = 0; g < G; ++g) {
        gx[g] = gt[(base_task + g) * 4 + 0];
        gy[g] = gt[(base_task + g) * 4 + 1];
    }

    if (tid < G) s_cnt[tid] = 0;
    __syncthreads();

    const float* pb = pred + (size_t)b * NPRED * 4;

    // ---- Phase 1: one shared pass, 4 gts per pred, 16 preds per thread ----
    const float T2 = T0SQ;
    for (int base = 0; base < NPRED; base += 8 * THREADS) {   // 2 iterations
        float2 v[8];
        #pragma unroll
        for (int k = 0; k < 8; ++k)
            v[k] = *reinterpret_cast<const float2*>(
                pb + (size_t)(base + k * THREADS + tid) * 4);  // 8 in flight
        #pragma unroll
        for (int k = 0; k < 8; ++k) {
            const int i = base + k * THREADS + tid;
            #pragma unroll
            for (int g = 0; g < G; ++g) {
                float dx = __fsub_rn(gx[g], v[k].x);
                float dy = __fsub_rn(gy[g], v[k].y);
                if (fmaf(dx, dx, dy * dy) < T2) {
                    // numpy-exact f32 key: sqrt((dx*dx)+(dy*dy)), no FMA
                    float d = __fsqrt_rn(__fadd_rn(__fmul_rn(dx, dx),
                                                   __fmul_rn(dy, dy)));
                    int pos = atomicAdd(&s_cnt[g], 1);
                    if (pos < CAP)
                        cand[g][pos] =
                            ((u64)__float_as_uint(d) << 32) | (unsigned)i;
                }
            }
        }
    }
    __syncthreads();

    // Waves 4..15 are done; waves 0..3 own gt w from here (all wave-local).
    const int w    = tid >> 6;
    const int lane = tid & 63;
    if (w >= G) return;

    // ---- Phase 1b: wave-local retry (rare: near-edge/corner gts) ----
    int C = s_cnt[w];
    float T2w = T0SQ;
    for (int attempt = 0; attempt < 8 && (C < KSEL || C > CAP); ++attempt) {
        T2w = (C < KSEL) ? T2w * 4.0f : T2w * 0.25f;
        if (lane == 0) s_cnt[w] = 0;
        asm volatile("s_waitcnt lgkmcnt(0)" ::: "memory");
        __builtin_amdgcn_wave_barrier();
        for (int i = lane; i < NPRED; i += 64) {
            const float2 p = *reinterpret_cast<const float2*>(pb + (size_t)i * 4);
            float dx = __fsub_rn(gx[w], p.x), dy = __fsub_rn(gy[w], p.y);
            if (fmaf(dx, dx, dy * dy) < T2w) {
                float d = __fsqrt_rn(__fadd_rn(__fmul_rn(dx, dx),
                                               __fmul_rn(dy, dy)));
                int pos = atomicAdd(&s_cnt[w], 1);
                if (pos < CAP)
                    cand[w][pos] = ((u64)__float_as_uint(d) << 32) | (unsigned)i;
            }
        }
        asm volatile("s_waitcnt lgkmcnt(0)" ::: "memory");
        __builtin_amdgcn_wave_barrier();
        C = s_cnt[w];
    }
    if (C > CAP) C = CAP;   // safety only

    // ---- Phase 2: wave-local O(C^2) rank selection (unique keys) ----
    for (int ci = lane; ci < C; ci += 64) {
        const u64 key = cand[w][ci];
        int r = 0;
        for (int j = 0; j < C; ++j)
            r += (cand[w][j] < key) ? 1 : 0;   // broadcast LDS read
        if (r < KSEL) topk[w][r] = key;
    }
    asm volatile("s_waitcnt lgkmcnt(0)" ::: "memory");
    __builtin_amdgcn_wave_barrier();

    // ---- Phase 3: epilogue, wave w -> gt w, numpy-exact f32 ----
    const int task = base_task + w;
    const float* gtp = gt + task * 4;
    const float gcx = gtp[0], gcy = gtp[1], gw = gtp[2], gh = gtp[3];

    const u64 key = topk[w][lane];
    const int idx = (int)(key & (u64)(NPRED - 1));

    const float gx1 = __fsub_rn(gcx, __fmul_rn(0.5f, gw));
    const float gy1 = __fsub_rn(gcy, __fmul_rn(0.5f, gh));
    const float gx2 = __fadd_rn(gcx, __fmul_rn(0.5f, gw));
    const float gy2 = __fadd_rn(gcy, __fmul_rn(0.5f, gh));

    const float4 kb = *reinterpret_cast<const float4*>(pb + (size_t)idx * 4);
    const float kcx = kb.x, kcy = kb.y;
    float kx1 = __fsub_rn(kb.x, __fmul_rn(0.5f, kb.z));
    float ky1 = __fsub_rn(kb.y, __fmul_rn(0.5f, kb.w));
    float kx2 = __fadd_rn(kb.x, __fmul_rn(0.5f, kb.z));
    float ky2 = __fadd_rn(kb.y, __fmul_rn(0.5f, kb.w));
    float ltx = fmaxf(gx1, kx1), lty = fmaxf(gy1, ky1);
    float rbx = fminf(gx2, kx2), rby = fminf(gy2, ky2);
    float wx = fmaxf(__fsub_rn(rbx, ltx), 0.0f);
    float wy = fmaxf(__fsub_rn(rby, lty), 0.0f);
    float inter = __fmul_rn(wx, wy);
    float ag = __fmul_rn(__fsub_rn(gx2, gx1), __fsub_rn(gy2, gy1));
    float ak = __fmul_rn(__fsub_rn(kx2, kx1), __fsub_rn(ky2, ky1));
    float uni = __fsub_rn(__fadd_rn(ag, ak), inter);
    const float iou = __fdiv_rn(inter, uni);

    const float mean = __fdiv_rn(npsum64(iou, lane), 64.0f);
    const float dd   = __fsub_rn(iou, mean);
    const float var  = __fdiv_rn(npsum64(__fmul_rn(dd, dd), lane), 63.0f);
    const float thr  = __fadd_rn(mean, __fsqrt_rn(var));

    const bool inside = (gx1 <= kcx) && (kcx <= gx2) && (gy1 <= kcy) && (kcy <= gy2);
    const bool m = (iou >= thr) && inside;

    const int o = task * KSEL + lane;
    out[OUT_IOUS + o] = iou;
    out[OUT_MASK + o] = m ? 1.0f : 0.0f;
    out[OUT_KIDX + o] = (float)idx;
}

extern "C" void kernel_launch(void* const* d_in, const int* in_sizes, int n_in,
                              void* d_out, int out_size, void* d_ws, size_t ws_size,
                              hipStream_t stream) {
    const float* pred = (const float*)d_in[0];  // (16,16384,4) f32
    const float* gtb  = (const float*)d_in[1];  // (16,128,4)   f32
    float* out = (float*)d_out;
    hipLaunchKernelGGL(atss_fused, dim3(16 * NGT / G), dim3(THREADS), 0, stream,
                       pred, gtb, out);
}

// Round 9
// 38.366 us; speedup vs baseline: 2.3780x; 2.3780x over previous
//
#include <hip/hip_runtime.h>
#include <stdint.h>

#define NPRED   16384
#define NGT     128
#define KSEL    64
#define CAP     384
#define G       4          // gts per block (register-shared scan)
#define THREADS 1024       // 16 waves
#define CTARGET 170.0f     // target E[candidates] per gt (8 sigma above K=64)

typedef unsigned long long u64;

// Outputs (float32, concatenated): ious[16*128*64], mask[...], k_idx[...]
#define OUT_IOUS 0
#define OUT_MASK (16 * NGT * KSEL)
#define OUT_KIDX (2 * 16 * NGT * KSEL)

// Per-gt adaptive squared radius: solve area(disk(r) ∩ [0,1]^2) = CTARGET/NPRED
// via fixed-point on the separable clip approximation area ≈ pi r^2 fx fy.
// Exact at corners/edges; underestimates area in partial clip -> larger r
// (conservative). This is only OUR filter; exact top-k semantics come later.
__device__ __forceinline__ float adaptive_T2(float x, float y) {
    const float A = CTARGET / (float)NPRED;
    float r = __fsqrt_rn(A * (1.0f / 3.14159265f));
    #pragma unroll
    for (int it = 0; it < 3; ++it) {
        const float inv2r = 0.5f / r;
        float fx = (fminf(x + r, 1.0f) - fmaxf(x - r, 0.0f)) * inv2r;
        float fy = (fminf(y + r, 1.0f) - fmaxf(y - r, 0.0f)) * inv2r;
        fx = fmaxf(fx, 0.5f); fy = fmaxf(fy, 0.5f);
        r = __fsqrt_rn(A / (3.14159265f * fx * fy));
    }
    return r * r;
}

// numpy-exact pairwise sum of 64 per-lane values (n=64: 8 strided partials,
// then ((r0+r1)+(r2+r3)) + ((r4+r5)+(r6+r7))). All lanes return the sum.
// Validated bit-exact (absmax=0) in R2-R8.
__device__ __forceinline__ float npsum64(float v, int lane) {
    const int j = lane & 7;
    float r = __shfl(v, j, 64);                       // a[j]
    #pragma unroll
    for (int k = 1; k < 8; ++k)
        r = __fadd_rn(r, __shfl(v, j + 8 * k, 64));   // += a[j+8k], in order
    const float r0 = __shfl(r, 0, 64), r1 = __shfl(r, 1, 64),
                r2 = __shfl(r, 2, 64), r3 = __shfl(r, 3, 64),
                r4 = __shfl(r, 4, 64), r5 = __shfl(r, 5, 64),
                r6 = __shfl(r, 6, 64), r7 = __shfl(r, 7, 64);
    return __fadd_rn(__fadd_rn(__fadd_rn(r0, r1), __fadd_rn(r2, r3)),
                     __fadd_rn(__fadd_rn(r4, r5), __fadd_rn(r6, r7)));
}

__global__ __launch_bounds__(THREADS) void atss_fused(
    const float* __restrict__ pred,  // [16][16384][4] cxcywh
    const float* __restrict__ gt,    // [16][128][4]  cxcywh
    float* __restrict__ out)
{
    __shared__ u64 cand[G][CAP];
    __shared__ u64 topk[G][KSEL];
    __shared__ int s_cnt[G];

    const int tid  = threadIdx.x;
    const int bid  = blockIdx.x;
    const int base_task = bid * G;          // 4 consecutive gts, same batch
    const int b    = base_task >> 7;

    // gt centers + adaptive radii for the 4 gts (uniform scalar loads/math)
    float gx[G], gy[G], T2[G];
    #pragma unroll
    for (int g = 0; g < G; ++g) {
        gx[g] = gt[(base_task + g) * 4 + 0];
        gy[g] = gt[(base_task + g) * 4 + 1];
        T2[g] = adaptive_T2(gx[g], gy[g]);
    }

    if (tid < G) s_cnt[tid] = 0;
    __syncthreads();

    const float* pb = pred + (size_t)b * NPRED * 4;

    // ---- Phase 1: one shared pass, 4 gts per pred, 16 preds per thread ----
    for (int base = 0; base < NPRED; base += 8 * THREADS) {   // 2 iterations
        float2 v[8];
        #pragma unroll
        for (int k = 0; k < 8; ++k)
            v[k] = *reinterpret_cast<const float2*>(
                pb + (size_t)(base + k * THREADS + tid) * 4);  // 8 in flight
        #pragma unroll
        for (int k = 0; k < 8; ++k) {
            const int i = base + k * THREADS + tid;
            #pragma unroll
            for (int g = 0; g < G; ++g) {
                float dx = __fsub_rn(gx[g], v[k].x);
                float dy = __fsub_rn(gy[g], v[k].y);
                if (fmaf(dx, dx, dy * dy) < T2[g]) {
                    // numpy-exact f32 key: sqrt((dx*dx)+(dy*dy)), no FMA
                    float d = __fsqrt_rn(__fadd_rn(__fmul_rn(dx, dx),
                                                   __fmul_rn(dy, dy)));
                    int pos = atomicAdd(&s_cnt[g], 1);
                    if (pos < CAP)
                        cand[g][pos] =
                            ((u64)__float_as_uint(d) << 32) | (unsigned)i;
                }
            }
        }
    }
    __syncthreads();

    // Waves 4..15 are done; waves 0..3 own gt w from here (all wave-local).
    const int w    = tid >> 6;
    const int lane = tid & 63;
    if (w >= G) return;

    // ---- Phase 1b: wave-local retry (insurance; P ~ 1e-5 per gt) ----
    int C = s_cnt[w];
    float T2w = T2[w];
    for (int attempt = 0; attempt < 8 && (C < KSEL || C > CAP); ++attempt) {
        T2w = (C < KSEL) ? T2w * 2.0f : T2w * 0.5f;
        if (lane == 0) s_cnt[w] = 0;
        asm volatile("s_waitcnt lgkmcnt(0)" ::: "memory");
        __builtin_amdgcn_wave_barrier();
        for (int base = 0; base < NPRED; base += 8 * 64) {    // MLP-8 rescan
            float2 v[8];
            #pragma unroll
            for (int k = 0; k < 8; ++k)
                v[k] = *reinterpret_cast<const float2*>(
                    pb + (size_t)(base + k * 64 + lane) * 4);
            #pragma unroll
            for (int k = 0; k < 8; ++k) {
                const int i = base + k * 64 + lane;
                float dx = __fsub_rn(gx[w], v[k].x);
                float dy = __fsub_rn(gy[w], v[k].y);
                if (fmaf(dx, dx, dy * dy) < T2w) {
                    float d = __fsqrt_rn(__fadd_rn(__fmul_rn(dx, dx),
                                                   __fmul_rn(dy, dy)));
                    int pos = atomicAdd(&s_cnt[w], 1);
                    if (pos < CAP)
                        cand[w][pos] =
                            ((u64)__float_as_uint(d) << 32) | (unsigned)i;
                }
            }
        }
        asm volatile("s_waitcnt lgkmcnt(0)" ::: "memory");
        __builtin_amdgcn_wave_barrier();
        C = s_cnt[w];
    }
    if (C > CAP) C = CAP;   // safety only

    // ---- Phase 2: wave-local O(C^2) rank selection (unique keys) ----
    for (int ci = lane; ci < C; ci += 64) {
        const u64 key = cand[w][ci];
        int r = 0;
        for (int j = 0; j < C; ++j)
            r += (cand[w][j] < key) ? 1 : 0;   // broadcast LDS read
        if (r < KSEL) topk[w][r] = key;
    }
    asm volatile("s_waitcnt lgkmcnt(0)" ::: "memory");
    __builtin_amdgcn_wave_barrier();

    // ---- Phase 3: epilogue, wave w -> gt w, numpy-exact f32 ----
    const int task = base_task + w;
    const float* gtp = gt + task * 4;
    const float gcx = gtp[0], gcy = gtp[1], gw = gtp[2], gh = gtp[3];

    const u64 key = topk[w][lane];
    const int idx = (int)(key & (u64)(NPRED - 1));

    const float gx1 = __fsub_rn(gcx, __fmul_rn(0.5f, gw));
    const float gy1 = __fsub_rn(gcy, __fmul_rn(0.5f, gh));
    const float gx2 = __fadd_rn(gcx, __fmul_rn(0.5f, gw));
    const float gy2 = __fadd_rn(gcy, __fmul_rn(0.5f, gh));

    const float4 kb = *reinterpret_cast<const float4*>(pb + (size_t)idx * 4);
    const float kcx = kb.x, kcy = kb.y;
    float kx1 = __fsub_rn(kb.x, __fmul_rn(0.5f, kb.z));
    float ky1 = __fsub_rn(kb.y, __fmul_rn(0.5f, kb.w));
    float kx2 = __fadd_rn(kb.x, __fmul_rn(0.5f, kb.z));
    float ky2 = __fadd_rn(kb.y, __fmul_rn(0.5f, kb.w));
    float ltx = fmaxf(gx1, kx1), lty = fmaxf(gy1, ky1);
    float rbx = fminf(gx2, kx2), rby = fminf(gy2, ky2);
    float wx = fmaxf(__fsub_rn(rbx, ltx), 0.0f);
    float wy = fmaxf(__fsub_rn(rby, lty), 0.0f);
    float inter = __fmul_rn(wx, wy);
    float ag = __fmul_rn(__fsub_rn(gx2, gx1), __fsub_rn(gy2, gy1));
    float ak = __fmul_rn(__fsub_rn(kx2, kx1), __fsub_rn(ky2, ky1));
    float uni = __fsub_rn(__fadd_rn(ag, ak), inter);
    const float iou = __fdiv_rn(inter, uni);

    const float mean = __fdiv_rn(npsum64(iou, lane), 64.0f);
    const float dd   = __fsub_rn(iou, mean);
    const float var  = __fdiv_rn(npsum64(__fmul_rn(dd, dd), lane), 63.0f);
    const float thr  = __fadd_rn(mean, __fsqrt_rn(var));

    const bool inside = (gx1 <= kcx) && (kcx <= gx2) && (gy1 <= kcy) && (kcy <= gy2);
    const bool m = (iou >= thr) && inside;

    const int o = task * KSEL + lane;
    out[OUT_IOUS + o] = iou;
    out[OUT_MASK + o] = m ? 1.0f : 0.0f;
    out[OUT_KIDX + o] = (float)idx;
}

extern "C" void kernel_launch(void* const* d_in, const int* in_sizes, int n_in,
                              void* d_out, int out_size, void* d_ws, size_t ws_size,
                              hipStream_t stream) {
    const float* pred = (const float*)d_in[0];  // (16,16384,4) f32
    const float* gtb  = (const float*)d_in[1];  // (16,128,4)   f32
    float* out = (float*)d_out;
    hipLaunchKernelGGL(atss_fused, dim3(16 * NGT / G), dim3(THREADS), 0, stream,
                       pred, gtb, out);
}

// Round 10
// 33.558 us; speedup vs baseline: 2.7188x; 1.1433x over previous
//
#include <hip/hip_runtime.h>
#include <stdint.h>

#define NPRED   16384
#define NGT     128
#define KSEL    64
#define CAP     384
#define G       4          // gts per block (register-shared scan)
#define THREADS 1024       // 16 waves
#define CTARGET 170.0f     // target E[candidates] per gt (8 sigma above K=64)

typedef unsigned long long u64;

// Outputs (float32, concatenated): ious[16*128*64], mask[...], k_idx[...]
#define OUT_IOUS 0
#define OUT_MASK (16 * NGT * KSEL)
#define OUT_KIDX (2 * 16 * NGT * KSEL)

// Per-gt adaptive squared radius: solve area(disk(r) ∩ [0,1]^2) = CTARGET/NPRED
// via fixed-point on the separable clip approximation area ≈ pi r^2 fx fy.
// Conservative (larger r) in partial-clip. Only OUR filter; exact top-k
// semantics come from the sort key.
__device__ __forceinline__ float adaptive_T2(float x, float y) {
    const float A = CTARGET / (float)NPRED;
    float r = __fsqrt_rn(A * (1.0f / 3.14159265f));
    #pragma unroll
    for (int it = 0; it < 3; ++it) {
        const float inv2r = 0.5f / r;
        float fx = (fminf(x + r, 1.0f) - fmaxf(x - r, 0.0f)) * inv2r;
        float fy = (fminf(y + r, 1.0f) - fmaxf(y - r, 0.0f)) * inv2r;
        fx = fmaxf(fx, 0.5f); fy = fmaxf(fy, 0.5f);
        r = __fsqrt_rn(A / (3.14159265f * fx * fy));
    }
    return r * r;
}

// numpy-exact pairwise sum of 64 per-lane values. Validated bit-exact R2-R9.
__device__ __forceinline__ float npsum64(float v, int lane) {
    const int j = lane & 7;
    float r = __shfl(v, j, 64);                       // a[j]
    #pragma unroll
    for (int k = 1; k < 8; ++k)
        r = __fadd_rn(r, __shfl(v, j + 8 * k, 64));   // += a[j+8k], in order
    const float r0 = __shfl(r, 0, 64), r1 = __shfl(r, 1, 64),
                r2 = __shfl(r, 2, 64), r3 = __shfl(r, 3, 64),
                r4 = __shfl(r, 4, 64), r5 = __shfl(r, 5, 64),
                r6 = __shfl(r, 6, 64), r7 = __shfl(r, 7, 64);
    return __fadd_rn(__fadd_rn(__fadd_rn(r0, r1), __fadd_rn(r2, r3)),
                     __fadd_rn(__fadd_rn(r4, r5), __fadd_rn(r6, r7)));
}

__global__ __launch_bounds__(THREADS) void atss_fused(
    const float* __restrict__ pred,  // [16][16384][4] cxcywh
    const float* __restrict__ gt,    // [16][128][4]  cxcywh
    float* __restrict__ out)
{
    __shared__ u64 cand[G][CAP];
    __shared__ u64 topk[G][KSEL];
    __shared__ int s_cnt[G];

    const int tid  = threadIdx.x;
    const int bid  = blockIdx.x;
    const int base_task = bid * G;          // 4 consecutive gts, same batch
    const int b    = base_task >> 7;

    // gt centers + adaptive radii for the 4 gts (uniform scalar loads/math)
    float gx[G], gy[G], T2[G];
    #pragma unroll
    for (int g = 0; g < G; ++g) {
        gx[g] = gt[(base_task + g) * 4 + 0];
        gy[g] = gt[(base_task + g) * 4 + 1];
        T2[g] = adaptive_T2(gx[g], gy[g]);
    }

    if (tid < G) s_cnt[tid] = 0;
    __syncthreads();

    const float* pb = pred + (size_t)b * NPRED * 4;
    const int w    = tid >> 6;
    const int lane = tid & 63;

    // ---- Phase 1: one shared pass, 4 gts per pred, 16 preds per thread ----
    for (int base = 0; base < NPRED; base += 8 * THREADS) {   // 2 iterations
        float2 v[8];
        #pragma unroll
        for (int k = 0; k < 8; ++k)
            v[k] = *reinterpret_cast<const float2*>(
                pb + (size_t)(base + k * THREADS + tid) * 4);  // 8 in flight
        #pragma unroll
        for (int k = 0; k < 8; ++k) {
            const int i = base + k * THREADS + tid;
            #pragma unroll
            for (int g = 0; g < G; ++g) {
                float dx = __fsub_rn(gx[g], v[k].x);
                float dy = __fsub_rn(gy[g], v[k].y);
                if (fmaf(dx, dx, dy * dy) < T2[g]) {
                    // numpy-exact f32 key: sqrt((dx*dx)+(dy*dy)), no FMA
                    float d = __fsqrt_rn(__fadd_rn(__fmul_rn(dx, dx),
                                                   __fmul_rn(dy, dy)));
                    int pos = atomicAdd(&s_cnt[g], 1);
                    if (pos < CAP)
                        cand[g][pos] =
                            ((u64)__float_as_uint(d) << 32) | (unsigned)i;
                }
            }
        }
    }
    __syncthreads();

    // ---- Phase 1b: wave-local retry, waves 0..3 only (P ~ 1e-5 per gt) ----
    if (w < G) {
        int C = s_cnt[w];
        float T2w = T2[w];
        for (int attempt = 0; attempt < 8 && (C < KSEL || C > CAP); ++attempt) {
            T2w = (C < KSEL) ? T2w * 2.0f : T2w * 0.5f;
            if (lane == 0) s_cnt[w] = 0;
            asm volatile("s_waitcnt lgkmcnt(0)" ::: "memory");
            __builtin_amdgcn_wave_barrier();
            for (int base = 0; base < NPRED; base += 8 * 64) {   // MLP-8 rescan
                float2 v[8];
                #pragma unroll
                for (int k = 0; k < 8; ++k)
                    v[k] = *reinterpret_cast<const float2*>(
                        pb + (size_t)(base + k * 64 + lane) * 4);
                #pragma unroll
                for (int k = 0; k < 8; ++k) {
                    const int i = base + k * 64 + lane;
                    float dx = __fsub_rn(gx[w], v[k].x);
                    float dy = __fsub_rn(gy[w], v[k].y);
                    if (fmaf(dx, dx, dy * dy) < T2w) {
                        float d = __fsqrt_rn(__fadd_rn(__fmul_rn(dx, dx),
                                                       __fmul_rn(dy, dy)));
                        int pos = atomicAdd(&s_cnt[w], 1);
                        if (pos < CAP)
                            cand[w][pos] =
                                ((u64)__float_as_uint(d) << 32) | (unsigned)i;
                    }
                }
            }
            asm volatile("s_waitcnt lgkmcnt(0)" ::: "memory");
            __builtin_amdgcn_wave_barrier();
            C = s_cnt[w];
        }
    }
    __syncthreads();    // publish final cand/s_cnt to all 16 waves

    // ---- Phase 2: rank selection across ALL 16 waves (4 sub-waves per gt).
    // Inner loop batches 8 independent LDS reads to break the ~120cy
    // single-outstanding ds_read latency chain (was ~25us serialized).
    {
        const int g2  = w & 3;          // gt handled by this wave
        const int sub = w >> 2;         // candidate-quarter handled
        int C = s_cnt[g2]; C = C > CAP ? CAP : C;
        for (int ci = sub * 64 + lane; ci < C; ci += 256) {
            const u64 key = cand[g2][ci];
            int r = 0, j = 0;
            for (; j + 8 <= C; j += 8) {
                const u64 k0 = cand[g2][j + 0], k1 = cand[g2][j + 1];
                const u64 k2 = cand[g2][j + 2], k3 = cand[g2][j + 3];
                const u64 k4 = cand[g2][j + 4], k5 = cand[g2][j + 5];
                const u64 k6 = cand[g2][j + 6], k7 = cand[g2][j + 7];
                r += (k0 < key) + (k1 < key) + (k2 < key) + (k3 < key)
                   + (k4 < key) + (k5 < key) + (k6 < key) + (k7 < key);
            }
            for (; j < C; ++j) r += (cand[g2][j] < key) ? 1 : 0;
            if (r < KSEL) topk[g2][r] = key;
        }
    }
    __syncthreads();    // publish topk

    if (w >= G) return; // waves 4..15 done

    // ---- Phase 3: epilogue, wave w -> gt w, numpy-exact f32 ----
    const int task = base_task + w;
    const float* gtp = gt + task * 4;
    const float gcx = gtp[0], gcy = gtp[1], gw = gtp[2], gh = gtp[3];

    const u64 key = topk[w][lane];
    const int idx = (int)(key & (u64)(NPRED - 1));

    const float gx1 = __fsub_rn(gcx, __fmul_rn(0.5f, gw));
    const float gy1 = __fsub_rn(gcy, __fmul_rn(0.5f, gh));
    const float gx2 = __fadd_rn(gcx, __fmul_rn(0.5f, gw));
    const float gy2 = __fadd_rn(gcy, __fmul_rn(0.5f, gh));

    const float4 kb = *reinterpret_cast<const float4*>(pb + (size_t)idx * 4);
    const float kcx = kb.x, kcy = kb.y;
    float kx1 = __fsub_rn(kb.x, __fmul_rn(0.5f, kb.z));
    float ky1 = __fsub_rn(kb.y, __fmul_rn(0.5f, kb.w));
    float kx2 = __fadd_rn(kb.x, __fmul_rn(0.5f, kb.z));
    float ky2 = __fadd_rn(kb.y, __fmul_rn(0.5f, kb.w));
    float ltx = fmaxf(gx1, kx1), lty = fmaxf(gy1, ky1);
    float rbx = fminf(gx2, kx2), rby = fminf(gy2, ky2);
    float wx = fmaxf(__fsub_rn(rbx, ltx), 0.0f);
    float wy = fmaxf(__fsub_rn(rby, lty), 0.0f);
    float inter = __fmul_rn(wx, wy);
    float ag = __fmul_rn(__fsub_rn(gx2, gx1), __fsub_rn(gy2, gy1));
    float ak = __fmul_rn(__fsub_rn(kx2, kx1), __fsub_rn(ky2, ky1));
    float uni = __fsub_rn(__fadd_rn(ag, ak), inter);
    const float iou = __fdiv_rn(inter, uni);

    const float mean = __fdiv_rn(npsum64(iou, lane), 64.0f);
    const float dd   = __fsub_rn(iou, mean);
    const float var  = __fdiv_rn(npsum64(__fmul_rn(dd, dd), lane), 63.0f);
    const float thr  = __fadd_rn(mean, __fsqrt_rn(var));

    const bool inside = (gx1 <= kcx) && (kcx <= gx2) && (gy1 <= kcy) && (kcy <= gy2);
    const bool m = (iou >= thr) && inside;

    const int o = task * KSEL + lane;
    out[OUT_IOUS + o] = iou;
    out[OUT_MASK + o] = m ? 1.0f : 0.0f;
    out[OUT_KIDX + o] = (float)idx;
}

extern "C" void kernel_launch(void* const* d_in, const int* in_sizes, int n_in,
                              void* d_out, int out_size, void* d_ws, size_t ws_size,
                              hipStream_t stream) {
    const float* pred = (const float*)d_in[0];  // (16,16384,4) f32
    const float* gtb  = (const float*)d_in[1];  // (16,128,4)   f32
    float* out = (float*)d_out;
    hipLaunchKernelGGL(atss_fused, dim3(16 * NGT / G), dim3(THREADS), 0, stream,
                       pred, gtb, out);
}

// Round 11
// 30.424 us; speedup vs baseline: 2.9989x; 1.1030x over previous
//
#include <hip/hip_runtime.h>
#include <stdint.h>

#define NPRED   16384
#define NGT     128
#define KSEL    64
#define CAP     384
#define G       2          // gts per block
#define THREADS 512        // 8 waves; 4 blocks/CU -> 32 waves/CU
#define NBLK    (16 * NGT / G)      // 1024 blocks
#define CTARGET 170.0f     // target E[candidates] per gt (8 sigma above K=64)

typedef unsigned long long u64;

// Outputs (float32, concatenated): ious[16*128*64], mask[...], k_idx[...]
#define OUT_IOUS 0
#define OUT_MASK (16 * NGT * KSEL)
#define OUT_KIDX (2 * 16 * NGT * KSEL)

// Per-gt adaptive squared radius: solve area(disk(r) ∩ [0,1]^2) = CTARGET/NPRED
// via fixed-point on the separable clip approximation area ≈ pi r^2 fx fy.
// Conservative in partial-clip. Only OUR filter; exactness comes from the key.
__device__ __forceinline__ float adaptive_T2(float x, float y) {
    const float A = CTARGET / (float)NPRED;
    float r = __fsqrt_rn(A * (1.0f / 3.14159265f));
    #pragma unroll
    for (int it = 0; it < 3; ++it) {
        const float inv2r = 0.5f / r;
        float fx = (fminf(x + r, 1.0f) - fmaxf(x - r, 0.0f)) * inv2r;
        float fy = (fminf(y + r, 1.0f) - fmaxf(y - r, 0.0f)) * inv2r;
        fx = fmaxf(fx, 0.5f); fy = fmaxf(fy, 0.5f);
        r = __fsqrt_rn(A / (3.14159265f * fx * fy));
    }
    return r * r;
}

// numpy-exact pairwise sum of 64 per-lane values. Validated bit-exact R2-R10.
__device__ __forceinline__ float npsum64(float v, int lane) {
    const int j = lane & 7;
    float r = __shfl(v, j, 64);                       // a[j]
    #pragma unroll
    for (int k = 1; k < 8; ++k)
        r = __fadd_rn(r, __shfl(v, j + 8 * k, 64));   // += a[j+8k], in order
    const float r0 = __shfl(r, 0, 64), r1 = __shfl(r, 1, 64),
                r2 = __shfl(r, 2, 64), r3 = __shfl(r, 3, 64),
                r4 = __shfl(r, 4, 64), r5 = __shfl(r, 5, 64),
                r6 = __shfl(r, 6, 64), r7 = __shfl(r, 7, 64);
    return __fadd_rn(__fadd_rn(__fadd_rn(r0, r1), __fadd_rn(r2, r3)),
                     __fadd_rn(__fadd_rn(r4, r5), __fadd_rn(r6, r7)));
}

__global__ __launch_bounds__(THREADS, 8) void atss_fused(
    const float* __restrict__ pred,  // [16][16384][4] cxcywh
    const float* __restrict__ gt,    // [16][128][4]  cxcywh
    float* __restrict__ out)
{
    __shared__ u64 cand[G][CAP];
    __shared__ u64 topk[G][KSEL];
    __shared__ int s_cnt[G];

    const int tid = threadIdx.x;
    // Bijective XCD swizzle (1024 = 8 x 128): each XCD gets 128 consecutive
    // gt-groups = 2 batches = 512 KB pred working set (fits 4 MB L2).
    const int bid  = ((blockIdx.x & 7) << 7) | (blockIdx.x >> 3);
    const int base_task = bid * G;          // 2 consecutive gts, same batch
    const int b    = base_task >> 7;

    float gx[G], gy[G], T2[G];
    #pragma unroll
    for (int g = 0; g < G; ++g) {
        gx[g] = gt[(base_task + g) * 4 + 0];
        gy[g] = gt[(base_task + g) * 4 + 1];
        T2[g] = adaptive_T2(gx[g], gy[g]);
    }

    if (tid < G) s_cnt[tid] = 0;
    __syncthreads();

    const float* pb = pred + (size_t)b * NPRED * 4;
    const int w    = tid >> 6;
    const int lane = tid & 63;

    // ---- Phase 1: shared scan, 2 gts per pred, 32 preds per thread.
    // Burst-8 loads made real: all 8 issued before any use (sched_barrier
    // keeps the scheduler from interleaving load->use to save registers).
    for (int base = 0; base < NPRED; base += 8 * THREADS) {   // 4 iterations
        float2 v[8];
        #pragma unroll
        for (int k = 0; k < 8; ++k)
            v[k] = *reinterpret_cast<const float2*>(
                pb + (size_t)(base + k * THREADS + tid) * 4);
        __builtin_amdgcn_sched_barrier(0);   // 8 loads genuinely in flight
        #pragma unroll
        for (int k = 0; k < 8; ++k) {
            const int i = base + k * THREADS + tid;
            #pragma unroll
            for (int g = 0; g < G; ++g) {
                float dx = __fsub_rn(gx[g], v[k].x);
                float dy = __fsub_rn(gy[g], v[k].y);
                if (fmaf(dx, dx, dy * dy) < T2[g]) {
                    // numpy-exact f32 key: sqrt((dx*dx)+(dy*dy)), no FMA
                    float d = __fsqrt_rn(__fadd_rn(__fmul_rn(dx, dx),
                                                   __fmul_rn(dy, dy)));
                    int pos = atomicAdd(&s_cnt[g], 1);
                    if (pos < CAP)
                        cand[g][pos] =
                            ((u64)__float_as_uint(d) << 32) | (unsigned)i;
                }
            }
        }
    }
    __syncthreads();

    // ---- Phase 1b: wave-local retry, waves 0..1 only (P ~ 1e-5 per gt) ----
    if (w < G) {
        int C = s_cnt[w];
        float T2w = T2[w];
        for (int attempt = 0; attempt < 8 && (C < KSEL || C > CAP); ++attempt) {
            T2w = (C < KSEL) ? T2w * 2.0f : T2w * 0.5f;
            if (lane == 0) s_cnt[w] = 0;
            asm volatile("s_waitcnt lgkmcnt(0)" ::: "memory");
            __builtin_amdgcn_wave_barrier();
            for (int base = 0; base < NPRED; base += 8 * 64) {   // MLP-8 rescan
                float2 v[8];
                #pragma unroll
                for (int k = 0; k < 8; ++k)
                    v[k] = *reinterpret_cast<const float2*>(
                        pb + (size_t)(base + k * 64 + lane) * 4);
                #pragma unroll
                for (int k = 0; k < 8; ++k) {
                    const int i = base + k * 64 + lane;
                    float dx = __fsub_rn(gx[w], v[k].x);
                    float dy = __fsub_rn(gy[w], v[k].y);
                    if (fmaf(dx, dx, dy * dy) < T2w) {
                        float d = __fsqrt_rn(__fadd_rn(__fmul_rn(dx, dx),
                                                       __fmul_rn(dy, dy)));
                        int pos = atomicAdd(&s_cnt[w], 1);
                        if (pos < CAP)
                            cand[w][pos] =
                                ((u64)__float_as_uint(d) << 32) | (unsigned)i;
                    }
                }
            }
            asm volatile("s_waitcnt lgkmcnt(0)" ::: "memory");
            __builtin_amdgcn_wave_barrier();
            C = s_cnt[w];
        }
    }
    __syncthreads();    // publish final cand/s_cnt to all 8 waves

    // ---- Phase 2: rank selection across all 8 waves (4 sub-waves per gt),
    // batched 8-wide LDS reads (breaks the ds_read latency chain) ----
    {
        const int g2  = w & (G - 1);    // gt handled by this wave
        const int sub = w >> 1;         // candidate-quarter (0..3)
        int C = s_cnt[g2]; C = C > CAP ? CAP : C;
        for (int ci = sub * 64 + lane; ci < C; ci += 256) {
            const u64 key = cand[g2][ci];
            int r = 0, j = 0;
            for (; j + 8 <= C; j += 8) {
                const u64 k0 = cand[g2][j + 0], k1 = cand[g2][j + 1];
                const u64 k2 = cand[g2][j + 2], k3 = cand[g2][j + 3];
                const u64 k4 = cand[g2][j + 4], k5 = cand[g2][j + 5];
                const u64 k6 = cand[g2][j + 6], k7 = cand[g2][j + 7];
                r += (k0 < key) + (k1 < key) + (k2 < key) + (k3 < key)
                   + (k4 < key) + (k5 < key) + (k6 < key) + (k7 < key);
            }
            for (; j < C; ++j) r += (cand[g2][j] < key) ? 1 : 0;
            if (r < KSEL) topk[g2][r] = key;
        }
    }
    __syncthreads();    // publish topk

    if (w >= G) return; // waves 2..7 done

    // ---- Phase 3: epilogue, wave w -> gt w, numpy-exact f32 ----
    const int task = base_task + w;
    const float* gtp = gt + task * 4;
    const float gcx = gtp[0], gcy = gtp[1], gw = gtp[2], gh = gtp[3];

    const u64 key = topk[w][lane];
    const int idx = (int)(key & (u64)(NPRED - 1));

    const float gx1 = __fsub_rn(gcx, __fmul_rn(0.5f, gw));
    const float gy1 = __fsub_rn(gcy, __fmul_rn(0.5f, gh));
    const float gx2 = __fadd_rn(gcx, __fmul_rn(0.5f, gw));
    const float gy2 = __fadd_rn(gcy, __fmul_rn(0.5f, gh));

    const float4 kb = *reinterpret_cast<const float4*>(pb + (size_t)idx * 4);
    const float kcx = kb.x, kcy = kb.y;
    float kx1 = __fsub_rn(kb.x, __fmul_rn(0.5f, kb.z));
    float ky1 = __fsub_rn(kb.y, __fmul_rn(0.5f, kb.w));
    float kx2 = __fadd_rn(kb.x, __fmul_rn(0.5f, kb.z));
    float ky2 = __fadd_rn(kb.y, __fmul_rn(0.5f, kb.w));
    float ltx = fmaxf(gx1, kx1), lty = fmaxf(gy1, ky1);
    float rbx = fminf(gx2, kx2), rby = fminf(gy2, ky2);
    float wx = fmaxf(__fsub_rn(rbx, ltx), 0.0f);
    float wy = fmaxf(__fsub_rn(rby, lty), 0.0f);
    float inter = __fmul_rn(wx, wy);
    float ag = __fmul_rn(__fsub_rn(gx2, gx1), __fsub_rn(gy2, gy1));
    float ak = __fmul_rn(__fsub_rn(kx2, kx1), __fsub_rn(ky2, ky1));
    float uni = __fsub_rn(__fadd_rn(ag, ak), inter);
    const float iou = __fdiv_rn(inter, uni);

    const float mean = __fdiv_rn(npsum64(iou, lane), 64.0f);
    const float dd   = __fsub_rn(iou, mean);
    const float var  = __fdiv_rn(npsum64(__fmul_rn(dd, dd), lane), 63.0f);
    const float thr  = __fadd_rn(mean, __fsqrt_rn(var));

    const bool inside = (gx1 <= kcx) && (kcx <= gx2) && (gy1 <= kcy) && (kcy <= gy2);
    const bool m = (iou >= thr) && inside;

    const int o = task * KSEL + lane;
    out[OUT_IOUS + o] = iou;
    out[OUT_MASK + o] = m ? 1.0f : 0.0f;
    out[OUT_KIDX + o] = (float)idx;
}

extern "C" void kernel_launch(void* const* d_in, const int* in_sizes, int n_in,
                              void* d_out, int out_size, void* d_ws, size_t ws_size,
                              hipStream_t stream) {
    const float* pred = (const float*)d_in[0];  // (16,16384,4) f32
    const float* gtb  = (const float*)d_in[1];  // (16,128,4)   f32
    float* out = (float*)d_out;
    hipLaunchKernelGGL(atss_fused, dim3(NBLK), dim3(THREADS), 0, stream,
                       pred, gtb, out);
}

// Round 12
// 27.038 us; speedup vs baseline: 3.3744x; 1.1252x over previous
//
#include <hip/hip_runtime.h>
#include <stdint.h>

#define NPRED   16384
#define NGT     128
#define KSEL    64
#define CAP     256
#define G       2          // gts per block
#define THREADS 512        // 8 waves; 4 blocks/CU -> 32 waves/CU
#define NBLK    (16 * NGT / G)      // 1024 blocks
#define RND     (NPRED / (4 * THREADS))   // 8 pipelined rounds of 4 preds/thread
#define CTARGET 128.0f     // target E[candidates] per gt (5.7 sigma above K=64)

typedef unsigned long long u64;

// Outputs (float32, concatenated): ious[16*128*64], mask[...], k_idx[...]
#define OUT_IOUS 0
#define OUT_MASK (16 * NGT * KSEL)
#define OUT_KIDX (2 * 16 * NGT * KSEL)

// Per-gt adaptive squared radius: solve area(disk(r) ∩ [0,1]^2) = CTARGET/NPRED
// via fixed-point on the separable clip approximation area ≈ pi r^2 fx fy.
// Conservative in partial-clip. Only OUR filter; exactness comes from the key.
__device__ __forceinline__ float adaptive_T2(float x, float y) {
    const float A = CTARGET / (float)NPRED;
    float r = __fsqrt_rn(A * (1.0f / 3.14159265f));
    #pragma unroll
    for (int it = 0; it < 3; ++it) {
        const float inv2r = 0.5f / r;
        float fx = (fminf(x + r, 1.0f) - fmaxf(x - r, 0.0f)) * inv2r;
        float fy = (fminf(y + r, 1.0f) - fmaxf(y - r, 0.0f)) * inv2r;
        fx = fmaxf(fx, 0.5f); fy = fmaxf(fy, 0.5f);
        r = __fsqrt_rn(A / (3.14159265f * fx * fy));
    }
    return r * r;
}

// numpy-exact pairwise sum of 64 per-lane values. Validated bit-exact R2-R11.
__device__ __forceinline__ float npsum64(float v, int lane) {
    const int j = lane & 7;
    float r = __shfl(v, j, 64);                       // a[j]
    #pragma unroll
    for (int k = 1; k < 8; ++k)
        r = __fadd_rn(r, __shfl(v, j + 8 * k, 64));   // += a[j+8k], in order
    const float r0 = __shfl(r, 0, 64), r1 = __shfl(r, 1, 64),
                r2 = __shfl(r, 2, 64), r3 = __shfl(r, 3, 64),
                r4 = __shfl(r, 4, 64), r5 = __shfl(r, 5, 64),
                r6 = __shfl(r, 6, 64), r7 = __shfl(r, 7, 64);
    return __fadd_rn(__fadd_rn(__fadd_rn(r0, r1), __fadd_rn(r2, r3)),
                     __fadd_rn(__fadd_rn(r4, r5), __fadd_rn(r6, r7)));
}

__global__ __launch_bounds__(THREADS, 8) void atss_fused(
    const float* __restrict__ pred,  // [16][16384][4] cxcywh
    const float* __restrict__ gt,    // [16][128][4]  cxcywh
    float* __restrict__ out)
{
    __shared__ u64 cand[G][CAP];
    __shared__ u64 topk[G][KSEL];
    __shared__ int s_cnt[G];

    const int tid = threadIdx.x;
    // Bijective XCD swizzle (1024 = 8 x 128): each XCD gets 128 consecutive
    // gt-groups = 2 batches = 512 KB pred working set (fits 4 MB L2).
    const int bid  = ((blockIdx.x & 7) << 7) | (blockIdx.x >> 3);
    const int base_task = bid * G;          // 2 consecutive gts, same batch
    const int b    = base_task >> 7;
    // Stagger: co-XCD blocks start the panel at different offsets to spread
    // the co-phased L2 request bursts across the panel.
    const int off  = ((blockIdx.x >> 3) & 7) << 11;

    float gx[G], gy[G], T2[G];
    #pragma unroll
    for (int g = 0; g < G; ++g) {
        gx[g] = gt[(base_task + g) * 4 + 0];
        gy[g] = gt[(base_task + g) * 4 + 1];
        T2[g] = adaptive_T2(gx[g], gy[g]);
    }

    if (tid < G) s_cnt[tid] = 0;
    __syncthreads();

    const float* pb = pred + (size_t)b * NPRED * 4;
    const int w    = tid >> 6;
    const int lane = tid & 63;

    // ---- Phase 1: pipelined shared scan (2 gts/pred, 32 preds/thread).
    // Ping-pong 4-load bursts: next burst issued BEFORE consuming current,
    // so >=4 loads stay in flight continuously (no stop-and-go drain).
    {
        float2 va[4], vb[4];
        int ia[4], ib[4];
        #pragma unroll
        for (int k = 0; k < 4; ++k) {
            ia[k] = (k * THREADS + tid + off) & (NPRED - 1);
            va[k] = *reinterpret_cast<const float2*>(pb + (size_t)ia[k] * 4);
        }
        #pragma unroll
        for (int r = 0; r < RND; ++r) {
            if (r + 1 < RND) {
                #pragma unroll
                for (int k = 0; k < 4; ++k) {
                    ib[k] = ((r + 1) * 4 * THREADS + k * THREADS + tid + off)
                            & (NPRED - 1);
                    vb[k] = *reinterpret_cast<const float2*>(
                        pb + (size_t)ib[k] * 4);
                }
            }
            __builtin_amdgcn_sched_barrier(0);   // loads before consumes
            #pragma unroll
            for (int k = 0; k < 4; ++k) {
                #pragma unroll
                for (int g = 0; g < G; ++g) {
                    float dx = __fsub_rn(gx[g], va[k].x);
                    float dy = __fsub_rn(gy[g], va[k].y);
                    if (fmaf(dx, dx, dy * dy) < T2[g]) {
                        // numpy-exact f32 key: sqrt((dx*dx)+(dy*dy)), no FMA
                        float d = __fsqrt_rn(__fadd_rn(__fmul_rn(dx, dx),
                                                       __fmul_rn(dy, dy)));
                        int pos = atomicAdd(&s_cnt[g], 1);
                        if (pos < CAP)
                            cand[g][pos] = ((u64)__float_as_uint(d) << 32)
                                         | (unsigned)ia[k];
                    }
                }
            }
            #pragma unroll
            for (int k = 0; k < 4; ++k) { va[k] = vb[k]; ia[k] = ib[k]; }
        }
    }
    __syncthreads();

    // ---- Phase 1b: wave-local retry, waves 0..G-1 only (P ~ 1e-5 per gt) ----
    if (w < G) {
        int C = s_cnt[w];
        float T2w = T2[w];
        for (int attempt = 0; attempt < 8 && (C < KSEL || C > CAP); ++attempt) {
            T2w = (C < KSEL) ? T2w * 2.0f : T2w * 0.5f;
            if (lane == 0) s_cnt[w] = 0;
            asm volatile("s_waitcnt lgkmcnt(0)" ::: "memory");
            __builtin_amdgcn_wave_barrier();
            for (int base = 0; base < NPRED; base += 8 * 64) {   // MLP-8 rescan
                float2 v[8];
                #pragma unroll
                for (int k = 0; k < 8; ++k)
                    v[k] = *reinterpret_cast<const float2*>(
                        pb + (size_t)(base + k * 64 + lane) * 4);
                #pragma unroll
                for (int k = 0; k < 8; ++k) {
                    const int i = base + k * 64 + lane;
                    float dx = __fsub_rn(gx[w], v[k].x);
                    float dy = __fsub_rn(gy[w], v[k].y);
                    if (fmaf(dx, dx, dy * dy) < T2w) {
                        float d = __fsqrt_rn(__fadd_rn(__fmul_rn(dx, dx),
                                                       __fmul_rn(dy, dy)));
                        int pos = atomicAdd(&s_cnt[w], 1);
                        if (pos < CAP)
                            cand[w][pos] =
                                ((u64)__float_as_uint(d) << 32) | (unsigned)i;
                    }
                }
            }
            asm volatile("s_waitcnt lgkmcnt(0)" ::: "memory");
            __builtin_amdgcn_wave_barrier();
            C = s_cnt[w];
        }
    }
    __syncthreads();    // publish final cand/s_cnt to all 8 waves

    // ---- Phase 2: rank selection, 4 sub-waves per gt, batch-16 LDS reads
    // (one dependent-latency stall per 16 keys instead of per 8) ----
    {
        const int g2  = w & (G - 1);    // gt handled by this wave
        const int sub = w >> 1;         // candidate-quarter (0..3)
        int C = s_cnt[g2]; C = C > CAP ? CAP : C;
        for (int ci = sub * 64 + lane; ci < C; ci += 256) {
            const u64 key = cand[g2][ci];
            int r = 0, j = 0;
            for (; j + 16 <= C; j += 16) {
                u64 kk[16];
                #pragma unroll
                for (int t = 0; t < 16; ++t) kk[t] = cand[g2][j + t];
                #pragma unroll
                for (int t = 0; t < 16; ++t) r += (kk[t] < key) ? 1 : 0;
            }
            for (; j < C; ++j) r += (cand[g2][j] < key) ? 1 : 0;
            if (r < KSEL) topk[g2][r] = key;
        }
    }
    __syncthreads();    // publish topk

    if (w >= G) return; // waves G..7 done

    // ---- Phase 3: epilogue, wave w -> gt w, numpy-exact f32 ----
    const int task = base_task + w;
    const float* gtp = gt + task * 4;
    const float gcx = gtp[0], gcy = gtp[1], gw = gtp[2], gh = gtp[3];

    const u64 key = topk[w][lane];
    const int idx = (int)(key & (u64)(NPRED - 1));

    const float gx1 = __fsub_rn(gcx, __fmul_rn(0.5f, gw));
    const float gy1 = __fsub_rn(gcy, __fmul_rn(0.5f, gh));
    const float gx2 = __fadd_rn(gcx, __fmul_rn(0.5f, gw));
    const float gy2 = __fadd_rn(gcy, __fmul_rn(0.5f, gh));

    const float4 kb = *reinterpret_cast<const float4*>(pb + (size_t)idx * 4);
    const float kcx = kb.x, kcy = kb.y;
    float kx1 = __fsub_rn(kb.x, __fmul_rn(0.5f, kb.z));
    float ky1 = __fsub_rn(kb.y, __fmul_rn(0.5f, kb.w));
    float kx2 = __fadd_rn(kb.x, __fmul_rn(0.5f, kb.z));
    float ky2 = __fadd_rn(kb.y, __fmul_rn(0.5f, kb.w));
    float ltx = fmaxf(gx1, kx1), lty = fmaxf(gy1, ky1);
    float rbx = fminf(gx2, kx2), rby = fminf(gy2, ky2);
    float wx = fmaxf(__fsub_rn(rbx, ltx), 0.0f);
    float wy = fmaxf(__fsub_rn(rby, lty), 0.0f);
    float inter = __fmul_rn(wx, wy);
    float ag = __fmul_rn(__fsub_rn(gx2, gx1), __fsub_rn(gy2, gy1));
    float ak = __fmul_rn(__fsub_rn(kx2, kx1), __fsub_rn(ky2, ky1));
    float uni = __fsub_rn(__fadd_rn(ag, ak), inter);
    const float iou = __fdiv_rn(inter, uni);

    const float mean = __fdiv_rn(npsum64(iou, lane), 64.0f);
    const float dd   = __fsub_rn(iou, mean);
    const float var  = __fdiv_rn(npsum64(__fmul_rn(dd, dd), lane), 63.0f);
    const float thr  = __fadd_rn(mean, __fsqrt_rn(var));

    const bool inside = (gx1 <= kcx) && (kcx <= gx2) && (gy1 <= kcy) && (kcy <= gy2);
    const bool m = (iou >= thr) && inside;

    const int o = task * KSEL + lane;
    out[OUT_IOUS + o] = iou;
    out[OUT_MASK + o] = m ? 1.0f : 0.0f;
    out[OUT_KIDX + o] = (float)idx;
}

extern "C" void kernel_launch(void* const* d_in, const int* in_sizes, int n_in,
                              void* d_out, int out_size, void* d_ws, size_t ws_size,
                              hipStream_t stream) {
    const float* pred = (const float*)d_in[0];  // (16,16384,4) f32
    const float* gtb  = (const float*)d_in[1];  // (16,128,4)   f32
    float* out = (float*)d_out;
    hipLaunchKernelGGL(atss_fused, dim3(NBLK), dim3(THREADS), 0, stream,
                       pred, gtb, out);
}